// Round 1
// baseline (1071.372 us; speedup 1.0000x reference)
//
#include <hip/hip_runtime.h>
#include <stdint.h>

#define T_STEPS 4
#define NTOK    8192
#define DMODEL  1024
#define NEXP    8
#define EFF     512
#define BMT     128                      // block tile rows (tokens); expert regions padded to 128
#define CAPTOT  (2*NTOK + NEXP*BMT)      // 17408 assignment slots incl. per-expert padding

typedef __attribute__((ext_vector_type(8))) short bf8_t;   // 8 bf16 (4 VGPRs) MFMA operand
typedef __attribute__((ext_vector_type(4))) float f32x4;   // MFMA accumulator

#define MFMA(a,b,c) __builtin_amdgcn_mfma_f32_16x16x32_bf16((a),(b),(c),0,0,0)

// ---------------- bf16 3-limb split helpers ----------------

__device__ __forceinline__ unsigned short bf16rn(float f) {
    unsigned u = __float_as_uint(f);
    unsigned r = u + 0x7fffu + ((u >> 16) & 1u);   // round-to-nearest-even
    return (unsigned short)(r >> 16);
}
__device__ __forceinline__ float bf2f(unsigned short h) {
    return __uint_as_float(((unsigned)h) << 16);
}
__device__ __forceinline__ unsigned pk(unsigned short a, unsigned short b) {
    return (unsigned)a | ((unsigned)b << 16);
}

// read 8 floats from src, split into 3 bf16 limbs, write 16B per limb
__device__ __forceinline__ void stage8_3limb(const float* __restrict__ src,
                                             unsigned short* d0, unsigned short* d1,
                                             unsigned short* d2) {
    float v[8];
    *(float4*)&v[0] = *(const float4*)(src + 0);
    *(float4*)&v[4] = *(const float4*)(src + 4);
    unsigned short h[8], m[8], l[8];
#pragma unroll
    for (int i = 0; i < 8; ++i) {
        unsigned short a = bf16rn(v[i]);
        float r1 = v[i] - bf2f(a);
        unsigned short b = bf16rn(r1);
        float r2 = r1 - bf2f(b);
        h[i] = a; m[i] = b; l[i] = bf16rn(r2);
    }
    *(uint4*)d0 = make_uint4(pk(h[0],h[1]), pk(h[2],h[3]), pk(h[4],h[5]), pk(h[6],h[7]));
    *(uint4*)d1 = make_uint4(pk(m[0],m[1]), pk(m[2],m[3]), pk(m[4],m[5]), pk(m[6],m[7]));
    *(uint4*)d2 = make_uint4(pk(l[0],l[1]), pk(l[2],l[3]), pk(l[4],l[5]), pk(l[6],l[7]));
}

// ---------------- weight limb pre-split (one-shot, streaming) ----------------
// 8 floats per thread; grid sized exactly: NEXP*EFF*DMODEL/8/256 = 2048 blocks per matrix.

__global__ void k_split(const float* __restrict__ w, unsigned short* __restrict__ h,
                        unsigned short* __restrict__ m, unsigned short* __restrict__ l) {
    size_t i = (size_t)(blockIdx.x * blockDim.x + threadIdx.x) * 8;
    stage8_3limb(w + i, h + i, m + i, l + i);
}

// ---------------- routing ----------------

__global__ void k_count(const int* __restrict__ idx, int* __restrict__ counts) {
    int n = blockIdx.x * blockDim.x + threadIdx.x;
    if (n >= NTOK) return;
    int e0 = idx[2*n], e1 = idx[2*n+1];
    atomicAdd(&counts[e0], 1);
    if (e1 != e0) atomicAdd(&counts[e1], 1);   // dedup duplicate top-k
}

__global__ void k_prefix(const int* __restrict__ counts, int* __restrict__ offsets) {
    if (threadIdx.x == 0) {
        int o = 0;
        for (int e = 0; e < NEXP; ++e) {
            offsets[e] = o;
            o += (counts[e] + BMT - 1) / BMT * BMT;   // pad each expert region to 128
        }
        offsets[NEXP] = o;
    }
}

__global__ void k_fill(const int* __restrict__ idx, const float* __restrict__ wts,
                       const int* __restrict__ offsets, int* __restrict__ cursors,
                       int* __restrict__ tok, float* __restrict__ wgt) {
    int n = blockIdx.x * blockDim.x + threadIdx.x;
    if (n >= NTOK) return;
    int e0 = idx[2*n], e1 = idx[2*n+1];
    float w0 = wts[2*n], w1 = wts[2*n+1];
    if (e0 == e1) w0 = __fadd_rn(w0, w1);      // reference scatter-add order
    int p0 = offsets[e0] + atomicAdd(&cursors[e0], 1);
    tok[p0] = n; wgt[p0] = w0;
    if (e1 != e0) {
        int p1 = offsets[e1] + atomicAdd(&cursors[e1], 1);
        tok[p1] = n; wgt[p1] = w1;
    }
}

// ---------------- up-proj (3-limb bf16 MFMA) + fused LIF -> bf16 spikes ----------------
// Block: 128 tokens x 128 features, K=1024 in 32-chunks. 4 waves, each 64x64 (4x4 MFMA tiles).
// A (x) split in-kernel; B (weights) pre-split limbs copied straight into LDS.

__global__ __launch_bounds__(256, 2)
void k_up(const float* __restrict__ x,
          const unsigned short* __restrict__ uwh, const unsigned short* __restrict__ uwm,
          const unsigned short* __restrict__ uwl,
          const int* __restrict__ offsets, const int* __restrict__ tok,
          unsigned short* __restrict__ spk) {
    const int m0 = blockIdx.x * BMT;
    const int ft = blockIdx.y;
    if (m0 >= offsets[NEXP]) return;
    int e = 0;
    for (int i = 1; i < NEXP; ++i) if (m0 >= offsets[i]) e = i;

    __shared__ unsigned short As[3][128][40];   // [limb][token][k], +8 pad (80B stride -> 2-way frag reads)
    __shared__ unsigned short Bs[3][128][40];   // [limb][feature][k]

    const int tid  = threadIdx.x;
    const int lane = tid & 63, wid = tid >> 6;
    const int quad = lane >> 4, l16 = lane & 15;
    const int mw = (wid & 1) * 64, nw = (wid >> 1) * 64;

    // staging roles: thread -> row r (0..127), 16-elem half
    const int r = tid >> 1, half = tid & 1;
    const int tokA = tok[m0 + r];
    const float* xbase = x + (size_t)tokA * DMODEL + half * 16;
    const size_t woff = ((size_t)e * EFF + ft * 128 + r) * DMODEL + half * 16;
    const unsigned short* bhp = uwh + woff;
    const unsigned short* bmp = uwm + woff;
    const unsigned short* blp = uwl + woff;

    f32x4 mem[4][4];
#pragma unroll
    for (int i = 0; i < 4; ++i)
#pragma unroll
        for (int j = 0; j < 4; ++j) mem[i][j] = (f32x4){0.f,0.f,0.f,0.f};

    for (int t = 0; t < T_STEPS; ++t) {
        f32x4 acc[4][4];
#pragma unroll
        for (int i = 0; i < 4; ++i)
#pragma unroll
            for (int j = 0; j < 4; ++j) acc[i][j] = (f32x4){0.f,0.f,0.f,0.f};

        const float* xrow = xbase + (size_t)t * NTOK * DMODEL;

        for (int kc = 0; kc < DMODEL; kc += 32) {
            __syncthreads();
            stage8_3limb(xrow + kc,     &As[0][r][half*16],   &As[1][r][half*16],   &As[2][r][half*16]);
            stage8_3limb(xrow + kc + 8, &As[0][r][half*16+8], &As[1][r][half*16+8], &As[2][r][half*16+8]);
            *(uint4*)&Bs[0][r][half*16]   = *(const uint4*)(bhp + kc);
            *(uint4*)&Bs[0][r][half*16+8] = *(const uint4*)(bhp + kc + 8);
            *(uint4*)&Bs[1][r][half*16]   = *(const uint4*)(bmp + kc);
            *(uint4*)&Bs[1][r][half*16+8] = *(const uint4*)(bmp + kc + 8);
            *(uint4*)&Bs[2][r][half*16]   = *(const uint4*)(blp + kc);
            *(uint4*)&Bs[2][r][half*16+8] = *(const uint4*)(blp + kc + 8);
            __syncthreads();

            bf8_t bh[4], bm[4], bl[4];
#pragma unroll
            for (int nt = 0; nt < 4; ++nt) {
                const int nr = nw + nt*16 + l16;
                bh[nt] = *(const bf8_t*)&Bs[0][nr][quad*8];
                bm[nt] = *(const bf8_t*)&Bs[1][nr][quad*8];
                bl[nt] = *(const bf8_t*)&Bs[2][nr][quad*8];
            }
#pragma unroll
            for (int mt = 0; mt < 4; ++mt) {
                const int mr = mw + mt*16 + l16;
                bf8_t ah = *(const bf8_t*)&As[0][mr][quad*8];
                bf8_t am = *(const bf8_t*)&As[1][mr][quad*8];
                bf8_t al = *(const bf8_t*)&As[2][mr][quad*8];
#pragma unroll
                for (int nt = 0; nt < 4; ++nt) {
                    f32x4 c = acc[mt][nt];
                    c = MFMA(ah, bh[nt], c);
                    c = MFMA(am, bh[nt], c);
                    c = MFMA(ah, bm[nt], c);
                    c = MFMA(am, bm[nt], c);
                    c = MFMA(al, bh[nt], c);
                    c = MFMA(ah, bl[nt], c);
                    acc[mt][nt] = c;
                }
            }
        }

        // fused LIF epilogue (C layout: row = quad*4+reg, col = l16)
#pragma unroll
        for (int mt = 0; mt < 4; ++mt)
#pragma unroll
            for (int nt = 0; nt < 4; ++nt)
#pragma unroll
                for (int reg = 0; reg < 4; ++reg) {
                    float mv = __fadd_rn(__fmul_rn(0.9f, mem[mt][nt][reg]), acc[mt][nt][reg]);
                    bool s = mv > 1.0f;
                    mem[mt][nt][reg] = __fsub_rn(mv, s ? 1.0f : 0.0f);
                    int row = m0 + mw + mt*16 + quad*4 + reg;
                    int col = ft*128 + nw + nt*16 + l16;
                    spk[((size_t)t * CAPTOT + row) * EFF + col] = s ? 0x3F80u : 0u;
                }
    }
}

// ---------------- down-proj (spikes exact bf16 x pre-split 3-limb weights) + fused LIF + scatter ----------------
// Block: 128 tokens x 64 d_model cols, K=512 in 32-chunks. 4 waves, each 64x32 (4x2 tiles).

__global__ __launch_bounds__(256, 3)
void k_dn(const unsigned short* __restrict__ spk,
          const unsigned short* __restrict__ dwh, const unsigned short* __restrict__ dwm,
          const unsigned short* __restrict__ dwl,
          const int* __restrict__ offsets, const int* __restrict__ tok,
          const float* __restrict__ wgt, float* __restrict__ out) {
    const int m0 = blockIdx.x * BMT;
    const int dt = blockIdx.y;
    if (m0 >= offsets[NEXP]) return;
    int e = 0;
    for (int i = 1; i < NEXP; ++i) if (m0 >= offsets[i]) e = i;

    __shared__ unsigned short As[128][40];      // spikes [token][k(f)]
    __shared__ unsigned short Bs[3][64][40];    // weights [limb][d][k(f)]

    const int tid  = threadIdx.x;
    const int lane = tid & 63, wid = tid >> 6;
    const int quad = lane >> 4, l16 = lane & 15;
    const int mw = (wid & 1) * 64, nw = (wid >> 1) * 32;

    const int r = tid >> 1, half = tid & 1;       // A stager: row, 16-elem half
    const int dr = tid >> 2, q = tid & 3;         // B stager: d-row, 8-elem quarter
    const unsigned short* arow = spk + (size_t)(m0 + r) * EFF + half * 16;
    const size_t doff = ((size_t)e * DMODEL + dt * 64 + dr) * EFF + q * 8;
    const unsigned short* bhp = dwh + doff;
    const unsigned short* bmp = dwm + doff;
    const unsigned short* blp = dwl + doff;

    // row metadata for epilogue scatter
    int   rn[4][4];
    float rw[4][4];
#pragma unroll
    for (int mt = 0; mt < 4; ++mt)
#pragma unroll
        for (int reg = 0; reg < 4; ++reg) {
            int rr = m0 + mw + mt*16 + quad*4 + reg;
            rn[mt][reg] = tok[rr];
            rw[mt][reg] = wgt[rr];
        }

    f32x4 mem[4][2];
#pragma unroll
    for (int i = 0; i < 4; ++i) { mem[i][0] = (f32x4){0.f,0.f,0.f,0.f}; mem[i][1] = (f32x4){0.f,0.f,0.f,0.f}; }

    for (int t = 0; t < T_STEPS; ++t) {
        f32x4 acc[4][2];
#pragma unroll
        for (int i = 0; i < 4; ++i) { acc[i][0] = (f32x4){0.f,0.f,0.f,0.f}; acc[i][1] = (f32x4){0.f,0.f,0.f,0.f}; }

        const unsigned short* at = arow + (size_t)t * CAPTOT * EFF;

        for (int kc = 0; kc < EFF; kc += 32) {
            __syncthreads();
            *(uint4*)&As[r][half*16 + 0] = *(const uint4*)(at + kc + 0);
            *(uint4*)&As[r][half*16 + 8] = *(const uint4*)(at + kc + 8);
            *(uint4*)&Bs[0][dr][q*8] = *(const uint4*)(bhp + kc);
            *(uint4*)&Bs[1][dr][q*8] = *(const uint4*)(bmp + kc);
            *(uint4*)&Bs[2][dr][q*8] = *(const uint4*)(blp + kc);
            __syncthreads();

            bf8_t bh[2], bm[2], bl[2];
#pragma unroll
            for (int nt = 0; nt < 2; ++nt) {
                const int nr = nw + nt*16 + l16;
                bh[nt] = *(const bf8_t*)&Bs[0][nr][quad*8];
                bm[nt] = *(const bf8_t*)&Bs[1][nr][quad*8];
                bl[nt] = *(const bf8_t*)&Bs[2][nr][quad*8];
            }
#pragma unroll
            for (int mt = 0; mt < 4; ++mt) {
                const int mr = mw + mt*16 + l16;
                bf8_t a = *(const bf8_t*)&As[mr][quad*8];
#pragma unroll
                for (int nt = 0; nt < 2; ++nt) {
                    f32x4 c = acc[mt][nt];
                    c = MFMA(a, bh[nt], c);
                    c = MFMA(a, bm[nt], c);
                    c = MFMA(a, bl[nt], c);
                    acc[mt][nt] = c;
                }
            }
        }

        // fused LIF + weighted sparse scatter
#pragma unroll
        for (int mt = 0; mt < 4; ++mt)
#pragma unroll
            for (int nt = 0; nt < 2; ++nt)
#pragma unroll
                for (int reg = 0; reg < 4; ++reg) {
                    float mv = __fadd_rn(__fmul_rn(0.9f, mem[mt][nt][reg]), acc[mt][nt][reg]);
                    bool s = mv > 1.0f;
                    mem[mt][nt][reg] = __fsub_rn(mv, s ? 1.0f : 0.0f);
                    float w = rw[mt][reg];
                    if (s && w != 0.0f) {
                        int col = dt*64 + nw + nt*16 + l16;
                        atomicAdd(out + ((size_t)t * NTOK + rn[mt][reg]) * DMODEL + col, w);
                    }
                }
    }
}

// ---------------- launch ----------------

extern "C" void kernel_launch(void* const* d_in, const int* in_sizes, int n_in,
                              void* d_out, int out_size, void* d_ws, size_t ws_size,
                              hipStream_t stream) {
    const float* x      = (const float*)d_in[0];
    const int*   idx    = (const int*)  d_in[1];
    const float* wts    = (const float*)d_in[2];
    const float* up_w   = (const float*)d_in[3];
    const float* down_w = (const float*)d_in[4];
    float* out = (float*)d_out;

    char* ws = (char*)d_ws;
    int*   counts  = (int*)(ws + 0);
    int*   cursors = (int*)(ws + 32);
    int*   offsets = (int*)(ws + 64);
    int*   tok     = (int*)(ws + 128);
    float* wgt     = (float*)(ws + 128 + (size_t)CAPTOT * 4);
    unsigned short* spk = (unsigned short*)(ws + 128 + (size_t)CAPTOT * 8);

    const size_t WSPK = (size_t)T_STEPS * CAPTOT * EFF * 2;             // 71.3 MB
    size_t base2 = 128 + (size_t)CAPTOT * 8 + WSPK;
    base2 = (base2 + 511) & ~(size_t)511;
    const size_t WLIMB = (size_t)NEXP * EFF * DMODEL * 2;               // 8.39 MB per limb
    unsigned short* uwh = (unsigned short*)(ws + base2);
    unsigned short* uwm = (unsigned short*)(ws + base2 + 1*WLIMB);
    unsigned short* uwl = (unsigned short*)(ws + base2 + 2*WLIMB);
    unsigned short* dwh = (unsigned short*)(ws + base2 + 3*WLIMB);
    unsigned short* dwm = (unsigned short*)(ws + base2 + 4*WLIMB);
    unsigned short* dwl = (unsigned short*)(ws + base2 + 5*WLIMB);
    // total ws: ~122 MB

    hipMemsetAsync(ws, 0, 128 + (size_t)CAPTOT * 8, stream);
    hipMemsetAsync(out, 0, (size_t)out_size * sizeof(float), stream);

    // one-shot weight limb split: 8 floats/thread, 2048 blocks each
    const int nsplit = NEXP * EFF * DMODEL / 8 / 256;
    k_split<<<nsplit, 256, 0, stream>>>(up_w,   uwh, uwm, uwl);
    k_split<<<nsplit, 256, 0, stream>>>(down_w, dwh, dwm, dwl);

    k_count <<<(NTOK + 255) / 256, 256, 0, stream>>>(idx, counts);
    k_prefix<<<1, 64, 0, stream>>>(counts, offsets);
    k_fill  <<<(NTOK + 255) / 256, 256, 0, stream>>>(idx, wts, offsets, cursors, tok, wgt);

    dim3 gup(CAPTOT / BMT, EFF / 128);      // (136, 4); tiles past used rows early-exit
    k_up<<<gup, 256, 0, stream>>>(x, uwh, uwm, uwl, offsets, tok, spk);

    dim3 gdn(CAPTOT / BMT, DMODEL / 64);    // (136, 16)
    k_dn<<<gdn, 256, 0, stream>>>(spk, dwh, dwm, dwl, offsets, tok, wgt, out);
}